// Round 7
// baseline (134.638 us; speedup 1.0000x reference)
//
#include <hip/hip_runtime.h>

// Fused capsule conv + dynamic routing, MFMA version, occupancy-max.
// x:      [8, 32, 8, 32, 32] f32   (bs, ci, ni, hi, wi)
// conv_w: [256, 8, 3, 3]     f32   (co*no, ni, kh, kw)
// bias:   [32, 8, 1, 1]      f32
// out:    [8, 32, 8, 32, 32] f32   (bs, co, no, ho, wo)
//
// R4 structure (122 us) + LDS aliasing: logits/routeT live in A's space
// (A is dead after the GEMM; one post-GEMM barrier makes the reuse safe).
// LDS 22KB -> 12.8KB, launch_bounds(256,8): 8 blocks/CU = 32 waves (HW max).
// Rationale: R4/R5 A/B showed the kernel is wave-slot-bound (VALU 43%,
// MFMA 8-15%, HBM 6% -- all unsaturated; idle = DS-latency + barrier drain).

typedef __attribute__((ext_vector_type(8))) short short8;
typedef __attribute__((ext_vector_type(4))) float f32x4;

#define LSTR 200   // A' row stride (ushort): 400 B
#define RSTR 36    // routeT row stride (f32)

__device__ __forceinline__ float bf2f(ushort h) {
    return __uint_as_float(((unsigned)h) << 16);
}
__device__ __forceinline__ ushort f2bf_rne(float f) {
    unsigned u = __float_as_uint(f);
    unsigned r = (u + 0x7fffu + ((u >> 16) & 1u)) >> 16;
    return (ushort)r;
}

__global__ void prep_w(const float* __restrict__ cw, ushort* __restrict__ wp) {
    int e = blockIdx.x * 256 + threadIdx.x;   // [col=256][k=96]
    int col = e / 96, k = e - col * 96;
    float v = (k < 72) ? cw[col * 72 + k] : 0.0f;
    wp[e] = f2bf_rne(v);
}

__global__ __launch_bounds__(256, 8)
void caps_mfma(const float* __restrict__ x,
               const ushort* __restrict__ wp,
               const float* __restrict__ bias,
               float* __restrict__ out)
{
    // A (12,800 B) is dead after the GEMM; logits (4,224 B) + routeT
    // (4,608 B) alias into it. Union size = 12,800 B total LDS.
    __shared__ ushort A[32 * LSTR];
    float* logits = reinterpret_cast<float*>(A);          // [ci][33]
    float* routeT = reinterpret_cast<float*>(A) + 1056;   // [co][RSTR]

    const int t   = threadIdx.x;
    const int bid = blockIdx.x;
    const int b   = bid >> 10;
    const int hw  = bid & 1023;
    const int h   = hw >> 5;
    const int w   = hw & 31;

    // ---- stage A' rows: thread t <-> (ci = t>>3, ni = t&7); truncating split
    {
        const int ci = t >> 3, ni = t & 7;
        const float* xb = x + (((size_t)((b * 32 + ci) * 8 + ni)) << 10);
        ushort* Ar = A + ci * LSTR;
        #pragma unroll
        for (int kh = 0; kh < 3; ++kh)
            #pragma unroll
            for (int kw = 0; kw < 3; ++kw) {
                int hy = h + kh - 1, wx = w + kw - 1;   // block-uniform bounds
                float v = 0.0f;
                if ((unsigned)hy < 32u && (unsigned)wx < 32u) v = xb[(hy << 5) + wx];
                unsigned u = __float_as_uint(v);
                ushort hi = (ushort)(u >> 16);          // trunc: exact split in f32
                float lo = v - bf2f(hi);
                int k = ni * 9 + kh * 3 + kw;
                Ar[k]      = hi;
                Ar[96 + k] = (ushort)(__float_as_uint(lo) >> 16);
            }
        if (ni < 6) {   // zero K-pads 72..95 and 168..191
            uint2 z; z.x = 0u; z.y = 0u;
            *reinterpret_cast<uint2*>(Ar + 72  + ni * 4) = z;
            *reinterpret_cast<uint2*>(Ar + 168 + ni * 4) = z;
        }
    }
    __syncthreads();

    const int lane = t & 63, wv = t >> 6;
    const int lc = lane & 15, grp = lane >> 4;
    const int no = lane & 7;
    const int par = (lane >> 3) & 1;

    // ---- conv GEMM: 3 k-steps x {hi, lo}; B-frags from global (L2-resident)
    f32x4 acc[2][4];
    #pragma unroll
    for (int m = 0; m < 2; ++m)
        #pragma unroll
        for (int j = 0; j < 4; ++j) acc[m][j] = (f32x4){0.f, 0.f, 0.f, 0.f};

    #pragma unroll
    for (int ks = 0; ks < 3; ++ks) {
        short8 bq[4];
        #pragma unroll
        for (int j = 0; j < 4; ++j) {
            int col = wv * 64 + j * 16 + lc;
            bq[j] = *reinterpret_cast<const short8*>(wp + col * 96 + ks * 32 + grp * 8);
        }
        short8 ah[2], al[2];
        #pragma unroll
        for (int m = 0; m < 2; ++m) {
            const ushort* ar = A + (m * 16 + lc) * LSTR + ks * 32 + grp * 8;
            ah[m] = *reinterpret_cast<const short8*>(ar);
            al[m] = *reinterpret_cast<const short8*>(ar + 96);
        }
        #pragma unroll
        for (int m = 0; m < 2; ++m)
            #pragma unroll
            for (int j = 0; j < 4; ++j) {
                acc[m][j] = __builtin_amdgcn_mfma_f32_16x16x32_bf16(ah[m], bq[j], acc[m][j], 0, 0, 0);
                acc[m][j] = __builtin_amdgcn_mfma_f32_16x16x32_bf16(al[m], bq[j], acc[m][j], 0, 0, 0);
            }
    }
    __syncthreads();   // A is dead from here; logits/routeT may reuse its LDS

    float bj[4];
    #pragma unroll
    for (int j = 0; j < 4; ++j) bj[j] = bias[wv * 64 + j * 16 + lc];

    const int ci_s = t >> 3, j_s = t & 7;
    float act_[4];

    // ================= iteration 0: route = 1/32 exactly =================
    #pragma unroll
    for (int j = 0; j < 4; ++j) {
        float p = acc[0][j][0] + acc[0][j][1] + acc[0][j][2] + acc[0][j][3]
                + acc[1][j][0] + acc[1][j][1] + acc[1][j][2] + acc[1][j][3];
        p += __shfl_xor(p, 16);
        p += __shfl_xor(p, 32);             // sum over 32 ci, all lanes
        p = p * 0.03125f + bj[j];
        float s2 = p * p;
        s2 += __shfl_xor(s2, 1);
        s2 += __shfl_xor(s2, 2);
        s2 += __shfl_xor(s2, 4);            // sum over no
        act_[j] = p * sqrtf(s2) / (1.0f + s2);
    }
    // distances -> logits (pure write; covers all 1024 (ci,co) entries)
    #pragma unroll
    for (int j = 0; j < 4; ++j) {
        float a = act_[j];
        float d[8];
        #pragma unroll
        for (int r = 0; r < 4; ++r) { d[r] = acc[0][j][r] * a; d[4 + r] = acc[1][j][r] * a; }
        // butterfly transpose-reduce over the 8-lane no-group
        const bool b4 = (no & 4) != 0, b2 = (no & 2) != 0, b1 = (no & 1) != 0;
        float e[4];
        #pragma unroll
        for (int k = 0; k < 4; ++k) {
            float keep = b4 ? d[k + 4] : d[k];
            float send = b4 ? d[k] : d[k + 4];
            e[k] = keep + __shfl_xor(send, 4);
        }
        float f[2];
        #pragma unroll
        for (int k = 0; k < 2; ++k) {
            float keep = b2 ? e[k + 2] : e[k];
            float send = b2 ? e[k] : e[k + 2];
            f[k] = keep + __shfl_xor(send, 2);
        }
        float keep = b1 ? f[1] : f[0];
        float send = b1 ? f[0] : f[1];
        float r = keep + __shfl_xor(send, 1);
        int ci_w = ((no >> 2) << 4) + (grp << 2) + (no & 3);
        int co   = (wv << 3) + 2 * j + par;
        logits[ci_w * 33 + co] = r;
    }
    __syncthreads();

    // ================= iterations 1 and 2 =================
    for (int it = 1; it <= 2; ++it) {
        // (a) softmax over co; store transposed routeT[co][ci]
        float l0 = logits[ci_s * 33 + j_s];
        float l1 = logits[ci_s * 33 + j_s + 8];
        float l2 = logits[ci_s * 33 + j_s + 16];
        float l3 = logits[ci_s * 33 + j_s + 24];
        float mx = fmaxf(fmaxf(l0, l1), fmaxf(l2, l3));
        mx = fmaxf(mx, __shfl_xor(mx, 1));
        mx = fmaxf(mx, __shfl_xor(mx, 2));
        mx = fmaxf(mx, __shfl_xor(mx, 4));
        float e0 = __expf(l0 - mx), e1 = __expf(l1 - mx);
        float e2 = __expf(l2 - mx), e3 = __expf(l3 - mx);
        float s = e0 + e1 + e2 + e3;
        s += __shfl_xor(s, 1); s += __shfl_xor(s, 2); s += __shfl_xor(s, 4);
        float inv = 1.0f / s;
        routeT[(j_s)      * RSTR + ci_s] = e0 * inv;
        routeT[(j_s + 8)  * RSTR + ci_s] = e1 * inv;
        routeT[(j_s + 16) * RSTR + ci_s] = e2 * inv;
        routeT[(j_s + 24) * RSTR + ci_s] = e3 * inv;
        __syncthreads();

        // (b) preactivate (ci-reduce xor16/32) + squash (no-reduce xor1/2/4)
        #pragma unroll
        for (int j = 0; j < 4; ++j) {
            int co = (wv << 3) + 2 * j + par;
            f32x4 r0 = *reinterpret_cast<const f32x4*>(routeT + co * RSTR + grp * 4);
            f32x4 r1 = *reinterpret_cast<const f32x4*>(routeT + co * RSTR + 16 + grp * 4);
            float p = 0.0f;
            #pragma unroll
            for (int r = 0; r < 4; ++r) p = fmaf(r0[r], acc[0][j][r], p);
            #pragma unroll
            for (int r = 0; r < 4; ++r) p = fmaf(r1[r], acc[1][j][r], p);
            p += __shfl_xor(p, 16);
            p += __shfl_xor(p, 32);
            p += bj[j];
            float s2 = p * p;
            s2 += __shfl_xor(s2, 1);
            s2 += __shfl_xor(s2, 2);
            s2 += __shfl_xor(s2, 4);
            act_[j] = p * sqrtf(s2) / (1.0f + s2);
        }
        if (it == 2) break;

        // (c) distances += (butterfly), accumulate into logits
        #pragma unroll
        for (int j = 0; j < 4; ++j) {
            float a = act_[j];
            float d[8];
            #pragma unroll
            for (int r = 0; r < 4; ++r) { d[r] = acc[0][j][r] * a; d[4 + r] = acc[1][j][r] * a; }
            const bool b4 = (no & 4) != 0, b2 = (no & 2) != 0, b1 = (no & 1) != 0;
            float e[4];
            #pragma unroll
            for (int k = 0; k < 4; ++k) {
                float keep = b4 ? d[k + 4] : d[k];
                float send = b4 ? d[k] : d[k + 4];
                e[k] = keep + __shfl_xor(send, 4);
            }
            float f[2];
            #pragma unroll
            for (int k = 0; k < 2; ++k) {
                float keep = b2 ? e[k + 2] : e[k];
                float send = b2 ? e[k] : e[k + 2];
                f[k] = keep + __shfl_xor(send, 2);
            }
            float keep = b1 ? f[1] : f[0];
            float send = b1 ? f[0] : f[1];
            float r = keep + __shfl_xor(send, 1);
            int ci_w = ((no >> 2) << 4) + (grp << 2) + (no & 3);
            int co   = (wv << 3) + 2 * j + par;
            logits[ci_w * 33 + co] += r;
        }
        __syncthreads();
    }

    // ---- output: act_ replicated over grp; grp 0 writes the wave's 64 cols
    if (grp == 0) {
        #pragma unroll
        for (int j = 0; j < 4; ++j) {
            int col = wv * 64 + j * 16 + lc;
            out[(((size_t)(b << 8) + col) << 10) + hw] = act_[j];
        }
    }
}

extern "C" void kernel_launch(void* const* d_in, const int* in_sizes, int n_in,
                              void* d_out, int out_size, void* d_ws, size_t ws_size,
                              hipStream_t stream) {
    const float* x    = (const float*)d_in[0];
    const float* cw   = (const float*)d_in[1];
    const float* bias = (const float*)d_in[2];
    float* out = (float*)d_out;
    ushort* wp = (ushort*)d_ws;           // 256*96*2 = 49,152 B
    (void)in_sizes; (void)n_in; (void)out_size; (void)ws_size;
    prep_w<<<96, 256, 0, stream>>>(cw, wp);
    caps_mfma<<<8192, 256, 0, stream>>>(x, wp, bias, out);
}

// Round 8
// 120.117 us; speedup vs baseline: 1.1209x; 1.1209x over previous
//
#include <hip/hip_runtime.h>

// Fused capsule conv + dynamic routing, MFMA + XCD-ownership swizzle.
// x:      [8, 32, 8, 32, 32] f32   (bs, ci, ni, hi, wi)
// conv_w: [256, 8, 3, 3]     f32   (co*no, ni, kh, kw)
// bias:   [32, 8, 1, 1]      f32
// out:    [8, 32, 8, 32, 32] f32   (bs, co, no, ho, wo)
//
// R6 structure + bijective XCD swizzle: bid = (raw&7)*1024 + raw>>3.
// Dispatch round-robins raw%8 across the 8 XCDs, so XCD k now owns ALL
// 1024 pixels of batch k: x slice (1 MB) + out slice (1 MB) are L2-resident
// per XCD. Fixes R6's FETCH blowup (73.5 MB, zero x reuse; demand 75 MB on
// an 8 MB tensor) and the 8x out write amplification (65 MB for 8 MB of
// stores at 4 KB stride: line-combining across hw-neighbor blocks needs
// them on the SAME XCD).

typedef __attribute__((ext_vector_type(8))) short short8;
typedef __attribute__((ext_vector_type(4))) float f32x4;

#define LSTR 200   // A' row stride (ushort): 400 B
#define RSTR 36    // routeT row stride (f32)

__device__ __forceinline__ float bf2f(ushort h) {
    return __uint_as_float(((unsigned)h) << 16);
}
__device__ __forceinline__ ushort f2bf_rne(float f) {
    unsigned u = __float_as_uint(f);
    unsigned r = (u + 0x7fffu + ((u >> 16) & 1u)) >> 16;
    return (ushort)r;
}

__global__ void prep_w(const float* __restrict__ cw, ushort* __restrict__ wp) {
    int e = blockIdx.x * 256 + threadIdx.x;   // [col=256][k=96]
    int col = e / 96, k = e - col * 96;
    float v = (k < 72) ? cw[col * 72 + k] : 0.0f;
    wp[e] = f2bf_rne(v);
}

__global__ __launch_bounds__(256, 8)
void caps_mfma(const float* __restrict__ x,
               const ushort* __restrict__ wp,
               const float* __restrict__ bias,
               float* __restrict__ out)
{
    // A (12,800 B) is dead after the GEMM; logits (4,224 B) + routeT
    // (4,608 B) alias into it. Union size = 12,800 B total LDS.
    __shared__ ushort A[32 * LSTR];
    float* logits = reinterpret_cast<float*>(A);          // [ci][33]
    float* routeT = reinterpret_cast<float*>(A) + 1056;   // [co][RSTR]

    const int t    = threadIdx.x;
    const int braw = blockIdx.x;
    // XCD-ownership swizzle: 8192 = 8 * 1024, bijective. XCD (braw&7) gets
    // the contiguous pixel range [ (braw&7)*1024, +1024 ) = one full batch.
    const int bid  = ((braw & 7) << 10) | (braw >> 3);
    const int b   = bid >> 10;
    const int hw  = bid & 1023;
    const int h   = hw >> 5;
    const int w   = hw & 31;

    // ---- stage A' rows: thread t <-> (ci = t>>3, ni = t&7); truncating split
    {
        const int ci = t >> 3, ni = t & 7;
        const float* xb = x + (((size_t)((b * 32 + ci) * 8 + ni)) << 10);
        ushort* Ar = A + ci * LSTR;
        #pragma unroll
        for (int kh = 0; kh < 3; ++kh)
            #pragma unroll
            for (int kw = 0; kw < 3; ++kw) {
                int hy = h + kh - 1, wx = w + kw - 1;   // block-uniform bounds
                float v = 0.0f;
                if ((unsigned)hy < 32u && (unsigned)wx < 32u) v = xb[(hy << 5) + wx];
                unsigned u = __float_as_uint(v);
                ushort hi = (ushort)(u >> 16);          // trunc: exact split in f32
                float lo = v - bf2f(hi);
                int k = ni * 9 + kh * 3 + kw;
                Ar[k]      = hi;
                Ar[96 + k] = (ushort)(__float_as_uint(lo) >> 16);
            }
        if (ni < 6) {   // zero K-pads 72..95 and 168..191
            uint2 z; z.x = 0u; z.y = 0u;
            *reinterpret_cast<uint2*>(Ar + 72  + ni * 4) = z;
            *reinterpret_cast<uint2*>(Ar + 168 + ni * 4) = z;
        }
    }
    __syncthreads();

    const int lane = t & 63, wv = t >> 6;
    const int lc = lane & 15, grp = lane >> 4;
    const int no = lane & 7;
    const int par = (lane >> 3) & 1;

    // ---- conv GEMM: 3 k-steps x {hi, lo}; B-frags from global (L2-resident)
    f32x4 acc[2][4];
    #pragma unroll
    for (int m = 0; m < 2; ++m)
        #pragma unroll
        for (int j = 0; j < 4; ++j) acc[m][j] = (f32x4){0.f, 0.f, 0.f, 0.f};

    #pragma unroll
    for (int ks = 0; ks < 3; ++ks) {
        short8 bq[4];
        #pragma unroll
        for (int j = 0; j < 4; ++j) {
            int col = wv * 64 + j * 16 + lc;
            bq[j] = *reinterpret_cast<const short8*>(wp + col * 96 + ks * 32 + grp * 8);
        }
        short8 ah[2], al[2];
        #pragma unroll
        for (int m = 0; m < 2; ++m) {
            const ushort* ar = A + (m * 16 + lc) * LSTR + ks * 32 + grp * 8;
            ah[m] = *reinterpret_cast<const short8*>(ar);
            al[m] = *reinterpret_cast<const short8*>(ar + 96);
        }
        #pragma unroll
        for (int m = 0; m < 2; ++m)
            #pragma unroll
            for (int j = 0; j < 4; ++j) {
                acc[m][j] = __builtin_amdgcn_mfma_f32_16x16x32_bf16(ah[m], bq[j], acc[m][j], 0, 0, 0);
                acc[m][j] = __builtin_amdgcn_mfma_f32_16x16x32_bf16(al[m], bq[j], acc[m][j], 0, 0, 0);
            }
    }
    __syncthreads();   // A is dead from here; logits/routeT may reuse its LDS

    float bj[4];
    #pragma unroll
    for (int j = 0; j < 4; ++j) bj[j] = bias[wv * 64 + j * 16 + lc];

    const int ci_s = t >> 3, j_s = t & 7;
    float act_[4];

    // ================= iteration 0: route = 1/32 exactly =================
    #pragma unroll
    for (int j = 0; j < 4; ++j) {
        float p = acc[0][j][0] + acc[0][j][1] + acc[0][j][2] + acc[0][j][3]
                + acc[1][j][0] + acc[1][j][1] + acc[1][j][2] + acc[1][j][3];
        p += __shfl_xor(p, 16);
        p += __shfl_xor(p, 32);             // sum over 32 ci, all lanes
        p = p * 0.03125f + bj[j];
        float s2 = p * p;
        s2 += __shfl_xor(s2, 1);
        s2 += __shfl_xor(s2, 2);
        s2 += __shfl_xor(s2, 4);            // sum over no
        act_[j] = p * sqrtf(s2) / (1.0f + s2);
    }
    // distances -> logits (pure write; covers all 1024 (ci,co) entries)
    #pragma unroll
    for (int j = 0; j < 4; ++j) {
        float a = act_[j];
        float d[8];
        #pragma unroll
        for (int r = 0; r < 4; ++r) { d[r] = acc[0][j][r] * a; d[4 + r] = acc[1][j][r] * a; }
        // butterfly transpose-reduce over the 8-lane no-group
        const bool b4 = (no & 4) != 0, b2 = (no & 2) != 0, b1 = (no & 1) != 0;
        float e[4];
        #pragma unroll
        for (int k = 0; k < 4; ++k) {
            float keep = b4 ? d[k + 4] : d[k];
            float send = b4 ? d[k] : d[k + 4];
            e[k] = keep + __shfl_xor(send, 4);
        }
        float f[2];
        #pragma unroll
        for (int k = 0; k < 2; ++k) {
            float keep = b2 ? e[k + 2] : e[k];
            float send = b2 ? e[k] : e[k + 2];
            f[k] = keep + __shfl_xor(send, 2);
        }
        float keep = b1 ? f[1] : f[0];
        float send = b1 ? f[0] : f[1];
        float r = keep + __shfl_xor(send, 1);
        int ci_w = ((no >> 2) << 4) + (grp << 2) + (no & 3);
        int co   = (wv << 3) + 2 * j + par;
        logits[ci_w * 33 + co] = r;
    }
    __syncthreads();

    // ================= iterations 1 and 2 =================
    for (int it = 1; it <= 2; ++it) {
        // (a) softmax over co; store transposed routeT[co][ci]
        float l0 = logits[ci_s * 33 + j_s];
        float l1 = logits[ci_s * 33 + j_s + 8];
        float l2 = logits[ci_s * 33 + j_s + 16];
        float l3 = logits[ci_s * 33 + j_s + 24];
        float mx = fmaxf(fmaxf(l0, l1), fmaxf(l2, l3));
        mx = fmaxf(mx, __shfl_xor(mx, 1));
        mx = fmaxf(mx, __shfl_xor(mx, 2));
        mx = fmaxf(mx, __shfl_xor(mx, 4));
        float e0 = __expf(l0 - mx), e1 = __expf(l1 - mx);
        float e2 = __expf(l2 - mx), e3 = __expf(l3 - mx);
        float s = e0 + e1 + e2 + e3;
        s += __shfl_xor(s, 1); s += __shfl_xor(s, 2); s += __shfl_xor(s, 4);
        float inv = 1.0f / s;
        routeT[(j_s)      * RSTR + ci_s] = e0 * inv;
        routeT[(j_s + 8)  * RSTR + ci_s] = e1 * inv;
        routeT[(j_s + 16) * RSTR + ci_s] = e2 * inv;
        routeT[(j_s + 24) * RSTR + ci_s] = e3 * inv;
        __syncthreads();

        // (b) preactivate (ci-reduce xor16/32) + squash (no-reduce xor1/2/4)
        #pragma unroll
        for (int j = 0; j < 4; ++j) {
            int co = (wv << 3) + 2 * j + par;
            f32x4 r0 = *reinterpret_cast<const f32x4*>(routeT + co * RSTR + grp * 4);
            f32x4 r1 = *reinterpret_cast<const f32x4*>(routeT + co * RSTR + 16 + grp * 4);
            float p = 0.0f;
            #pragma unroll
            for (int r = 0; r < 4; ++r) p = fmaf(r0[r], acc[0][j][r], p);
            #pragma unroll
            for (int r = 0; r < 4; ++r) p = fmaf(r1[r], acc[1][j][r], p);
            p += __shfl_xor(p, 16);
            p += __shfl_xor(p, 32);
            p += bj[j];
            float s2 = p * p;
            s2 += __shfl_xor(s2, 1);
            s2 += __shfl_xor(s2, 2);
            s2 += __shfl_xor(s2, 4);
            act_[j] = p * sqrtf(s2) / (1.0f + s2);
        }
        if (it == 2) break;

        // (c) distances += (butterfly), accumulate into logits
        #pragma unroll
        for (int j = 0; j < 4; ++j) {
            float a = act_[j];
            float d[8];
            #pragma unroll
            for (int r = 0; r < 4; ++r) { d[r] = acc[0][j][r] * a; d[4 + r] = acc[1][j][r] * a; }
            const bool b4 = (no & 4) != 0, b2 = (no & 2) != 0, b1 = (no & 1) != 0;
            float e[4];
            #pragma unroll
            for (int k = 0; k < 4; ++k) {
                float keep = b4 ? d[k + 4] : d[k];
                float send = b4 ? d[k] : d[k + 4];
                e[k] = keep + __shfl_xor(send, 4);
            }
            float f[2];
            #pragma unroll
            for (int k = 0; k < 2; ++k) {
                float keep = b2 ? e[k + 2] : e[k];
                float send = b2 ? e[k] : e[k + 2];
                f[k] = keep + __shfl_xor(send, 2);
            }
            float keep = b1 ? f[1] : f[0];
            float send = b1 ? f[0] : f[1];
            float r = keep + __shfl_xor(send, 1);
            int ci_w = ((no >> 2) << 4) + (grp << 2) + (no & 3);
            int co   = (wv << 3) + 2 * j + par;
            logits[ci_w * 33 + co] += r;
        }
        __syncthreads();
    }

    // ---- output: act_ replicated over grp; grp 0 writes the wave's 64 cols
    if (grp == 0) {
        #pragma unroll
        for (int j = 0; j < 4; ++j) {
            int col = wv * 64 + j * 16 + lc;
            out[(((size_t)(b << 8) + col) << 10) + hw] = act_[j];
        }
    }
}

extern "C" void kernel_launch(void* const* d_in, const int* in_sizes, int n_in,
                              void* d_out, int out_size, void* d_ws, size_t ws_size,
                              hipStream_t stream) {
    const float* x    = (const float*)d_in[0];
    const float* cw   = (const float*)d_in[1];
    const float* bias = (const float*)d_in[2];
    float* out = (float*)d_out;
    ushort* wp = (ushort*)d_ws;           // 256*96*2 = 49,152 B
    (void)in_sizes; (void)n_in; (void)out_size; (void)ws_size;
    prep_w<<<96, 256, 0, stream>>>(cw, wp);
    caps_mfma<<<8192, 256, 0, stream>>>(x, wp, bias, out);
}